// Round 7
// baseline (145.971 us; speedup 1.0000x reference)
//
#include <hip/hip_runtime.h>

#define NEG_INF (-3.402823466e+38f)

constexpr int Bc = 8, Cc = 512, Hc = 8, Dc = 64, Nc = 1024;
constexpr size_t QSZ = (size_t)Bc * Hc * Nc * Dc;  // 4,194,304 elements
constexpr size_t XTSZ = (size_t)8192 * 512;        // = QSZ
constexpr size_t WTSZ = (size_t)1536 * 512;

typedef __attribute__((ext_vector_type(8))) short short8;
typedef __attribute__((ext_vector_type(4))) float f32x4;
typedef unsigned short ushort_t;
typedef unsigned int uint_t;

// ------------------------------------------------------------ bf16 helpers
__device__ __forceinline__ ushort_t f2bf(float x) {
  uint_t u = __float_as_uint(x);
  u += 0x7FFFu + ((u >> 16) & 1u);  // round-to-nearest-even
  return (ushort_t)(u >> 16);
}
__device__ __forceinline__ float bf2f(ushort_t h) {
  return __uint_as_float(((uint_t)h) << 16);
}

// ---------------------------------------------------------------- zero output
__global__ void zero_out_k(float* __restrict__ o) {
  int i = blockIdx.x * 256 + threadIdx.x;
  if (i < Bc * Cc) o[i] = 0.f;
}

// ------------------------------------------------- transpose+split x -> xt
__global__ __launch_bounds__(256) void conv_x(const float* __restrict__ x,
                                              ushort_t* __restrict__ xh,
                                              ushort_t* __restrict__ xl) {
  __shared__ float t[64][65];
  const int b = blockIdx.z, c0 = blockIdx.y * 64, n0 = blockIdx.x * 64;
  const int tid = threadIdx.x;
  const int lc = tid & 63, lr = tid >> 6;
#pragma unroll
  for (int i = 0; i < 16; ++i) {
    int cc = lr + i * 4;
    t[cc][lc] = x[((size_t)(b * 512 + c0 + cc)) * 1024 + n0 + lc];
  }
  __syncthreads();
#pragma unroll
  for (int i = 0; i < 16; ++i) {
    int nn = lr + i * 4;
    float v = t[lc][nn];  // = x[b][c0+lc][n0+nn]
    ushort_t h = f2bf(v);
    ushort_t lo = f2bf(v - bf2f(h));
    size_t o = ((size_t)(b * 1024 + n0 + nn)) * 512 + c0 + lc;
    xh[o] = h;
    xl[o] = lo;
  }
}

// ------------------------------------------------- transpose+split W -> wt
__global__ __launch_bounds__(256) void conv_w(const float* __restrict__ wq,
                                              ushort_t* __restrict__ wh,
                                              ushort_t* __restrict__ wl) {
  __shared__ float t[64][65];
  const int c0 = blockIdx.y * 64, j0 = blockIdx.x * 64;
  const int tid = threadIdx.x;
  const int lj = tid & 63, lr = tid >> 6;
#pragma unroll
  for (int i = 0; i < 16; ++i) {
    int cc = lr + i * 4;
    t[cc][lj] = wq[(size_t)(c0 + cc) * 1536 + j0 + lj];
  }
  __syncthreads();
#pragma unroll
  for (int i = 0; i < 16; ++i) {
    int jj = lr + i * 4;
    float v = t[lj][jj];  // = W[c0+lj][j0+jj]
    ushort_t h = f2bf(v);
    ushort_t lo = f2bf(v - bf2f(h));
    size_t o = (size_t)(j0 + jj) * 512 + c0 + lj;
    wh[o] = h;
    wl[o] = lo;
  }
}

// ------------------------------------------------------ async stage helper
__device__ __forceinline__ void stage_tile(ushort_t* lds, const ushort_t* g,
                                           int tid) {
  typedef const __attribute__((address_space(1))) unsigned int GU;
  typedef __attribute__((address_space(3))) unsigned int LU;
  {
    int l = tid, r = l >> 2, c = (l & 3) * 8;
    __builtin_amdgcn_global_load_lds((GU*)(g + (size_t)r * 512 + c),
                                     (LU*)(lds + (size_t)l * 8), 16, 0, 0);
  }
  {
    int l = tid + 256, r = l >> 2, c = (l & 3) * 8;
    __builtin_amdgcn_global_load_lds((GU*)(g + (size_t)r * 512 + c),
                                     (LU*)(lds + (size_t)l * 8), 16, 0, 0);
  }
}

// ---------------------------------------------------------------- QKV GEMM
__global__ __launch_bounds__(256) void qkv_gemm_mfma(
    const ushort_t* __restrict__ xth, const ushort_t* __restrict__ xtl,
    const ushort_t* __restrict__ wth, const ushort_t* __restrict__ wtl,
    const float* __restrict__ bias, float* __restrict__ vbuf,
    ushort_t* __restrict__ khi, ushort_t* __restrict__ klo,
    ushort_t* __restrict__ qhi, ushort_t* __restrict__ qlo) {
  __shared__ __align__(16) ushort_t Ah[128 * 32];
  __shared__ __align__(16) ushort_t Al[128 * 32];
  __shared__ __align__(16) ushort_t Bh[128 * 32];
  __shared__ __align__(16) ushort_t Bl[128 * 32];

  const int m0 = blockIdx.x * 128, j0 = blockIdx.y * 128;
  const int tid = threadIdx.x;
  const int w = tid >> 6, l = tid & 63;
  const int lr = l & 15, lg = l >> 4;
  const int wr = w >> 1, wc = w & 1;

  f32x4 acc[4][4];
#pragma unroll
  for (int i = 0; i < 4; ++i)
#pragma unroll
    for (int j = 0; j < 4; ++j) acc[i][j] = (f32x4){0.f, 0.f, 0.f, 0.f};

  const ushort_t* xa = xth + (size_t)m0 * 512;
  const ushort_t* xb = xtl + (size_t)m0 * 512;
  const ushort_t* wa = wth + (size_t)j0 * 512;
  const ushort_t* wb = wtl + (size_t)j0 * 512;

  for (int s = 0; s < 16; ++s) {
    const int k0 = s * 32;
    stage_tile(Ah, xa + k0, tid);
    stage_tile(Al, xb + k0, tid);
    stage_tile(Bh, wa + k0, tid);
    stage_tile(Bl, wb + k0, tid);
    __syncthreads();  // drains vmcnt -> tiles resident

    short8 ah[4], al[4], bh[4], bl[4];
#pragma unroll
    for (int mi = 0; mi < 4; ++mi) {
      int ro = (wr * 64 + mi * 16 + lr) * 32 + lg * 8;
      ah[mi] = *(const short8*)&Ah[ro];
      al[mi] = *(const short8*)&Al[ro];
    }
#pragma unroll
    for (int ji = 0; ji < 4; ++ji) {
      int ro = (wc * 64 + ji * 16 + lr) * 32 + lg * 8;
      bh[ji] = *(const short8*)&Bh[ro];
      bl[ji] = *(const short8*)&Bl[ro];
    }
#pragma unroll
    for (int mi = 0; mi < 4; ++mi)
#pragma unroll
      for (int ji = 0; ji < 4; ++ji) {
        acc[mi][ji] = __builtin_amdgcn_mfma_f32_16x16x32_bf16(
            ah[mi], bh[ji], acc[mi][ji], 0, 0, 0);
        acc[mi][ji] = __builtin_amdgcn_mfma_f32_16x16x32_bf16(
            ah[mi], bl[ji], acc[mi][ji], 0, 0, 0);
        acc[mi][ji] = __builtin_amdgcn_mfma_f32_16x16x32_bf16(
            al[mi], bh[ji], acc[mi][ji], 0, 0, 0);
      }
    __syncthreads();
  }

  const int which = j0 >> 9;
  const int hh = ((j0 >> 6) + wc) & 7;
  float bias_r[4];
#pragma unroll
  for (int ji = 0; ji < 4; ++ji) bias_r[ji] = bias[j0 + wc * 64 + ji * 16 + lr];

#pragma unroll
  for (int mi = 0; mi < 4; ++mi)
#pragma unroll
    for (int t = 0; t < 4; ++t) {
      int m = m0 + wr * 64 + mi * 16 + lg * 4 + t;
      int b = m >> 10, n = m & 1023;
      size_t rb = ((size_t)(b * 8 + hh) << 16) + (size_t)n * 64;
#pragma unroll
      for (int ji = 0; ji < 4; ++ji) {
        float val = acc[mi][ji][t] + bias_r[ji];
        int dd = ji * 16 + lr;
        if (which == 2) {
          vbuf[rb + dd] = val;
        } else {
          ushort_t h = f2bf(val);
          ushort_t lo = f2bf(val - bf2f(h));
          if (which == 0) {
            qhi[rb + dd] = h;
            qlo[rb + dd] = lo;
          } else {
            khi[rb + dd] = h;
            klo[rb + dd] = lo;
          }
        }
      }
    }
}

// ------------------------------------------------------- packed-key top-4
__device__ __forceinline__ uint_t mono_f32(float x) {
  uint_t u = __float_as_uint(x);
  return u ^ (((uint_t)((int)u >> 31)) | 0x80000000u);
}
__device__ __forceinline__ void insk(uint_t k, uint_t& s0, uint_t& s1,
                                     uint_t& s2, uint_t& s3) {
  s3 = max(s3, k);
  uint_t t;
  t = max(s2, s3); s3 = min(s2, s3); s2 = t;
  t = max(s1, s2); s2 = min(s1, s2); s1 = t;
  t = max(s0, s1); s1 = min(s0, s1); s0 = t;
}

// -------------------------------------------------------- float insert4
__device__ __forceinline__ void insert4(float sc, int jv, float& s0, float& s1,
                                        float& s2, float& s3, int& i0, int& i1,
                                        int& i2, int& i3) {
  bool c = sc > s3;
  s3 = c ? sc : s3; i3 = c ? jv : i3;
  c = s3 > s2;
  { float t = c ? s2 : s3; s2 = c ? s3 : s2; s3 = t;
    int q = c ? i2 : i3; i2 = c ? i3 : i2; i3 = q; }
  c = s2 > s1;
  { float t = c ? s1 : s2; s1 = c ? s2 : s1; s2 = t;
    int q = c ? i1 : i2; i1 = c ? i2 : i1; i2 = q; }
  c = s1 > s0;
  { float t = c ? s0 : s1; s0 = c ? s1 : s0; s1 = t;
    int q = c ? i0 : i1; i0 = c ? i1 : i0; i1 = q; }
}

// ---------------------------------------------------------------- fused attn
// grid = 1024 (bh = bid&63 -> same-bh blocks share an XCD; rg = bid>>6).
// 512 thr = 8 waves: (w>>2) = 32-row half, (w&3) = 256-wide j-quarter.
// Stage A (prefilter): 1-pass bf16 scores, K double-buffered in regs,
//   packed-key lane-local top-4, shfl merge -> per-quarter top-4 in LDS.
// Stage B (rescore): 16 finalists/row rescored EXACTLY (hi+lo fp32 dots),
//   lane = cand*4 + dgroup, shfl-reduce; top-4 + softmax per row.
// Stage C: V-gather weighted sum, atomicAdd.
__global__ __launch_bounds__(512, 6) void attn_topk_mfma(
    const ushort_t* __restrict__ khi, const ushort_t* __restrict__ klo,
    const ushort_t* __restrict__ qhi, const ushort_t* __restrict__ qlo,
    const float* __restrict__ vg, float* __restrict__ out) {
  __shared__ uint_t kL[4][64][4];
  __shared__ float scL[64][16];
  __shared__ float wgt[64][4];
  __shared__ int widx[64][4];
  __shared__ float accb[8][64];

  const int bid = blockIdx.x;
  const int bh = bid & 63;
  const int rg = bid >> 6;
  const int tid = threadIdx.x;
  const int w = tid >> 6, l = tid & 63;
  const int lg = l >> 4, lr = l & 15;
  const int jq = w & 3, rowhalf = w >> 2;

  const int bhbase = bh << 16;  // bh * 1024 * 64 (fits int)
  const int rowbase = rg * 64 + rowhalf * 32;

  // Q hi fragments: 2 rowsets x 2 d-chunks (scan uses hi only)
  short8 qh[2][2];
#pragma unroll
  for (int rs = 0; rs < 2; ++rs)
#pragma unroll
    for (int c = 0; c < 2; ++c) {
      int a = bhbase + (rowbase + rs * 16 + lr) * 64 + c * 32 + lg * 8;
      qh[rs][c] = *(const short8*)(qhi + a);
    }

  uint_t K[2][4];
#pragma unroll
  for (int rs = 0; rs < 2; ++rs)
#pragma unroll
    for (int t = 0; t < 4; ++t) K[rs][t] = 0u;

  const uint_t jlane = (uint_t)(lg * 4);
  const int jt0 = jq * 16;

  // ---- Stage A: prefilter scan with register double-buffer of K
  {
    int ka0 = bhbase + (jt0 * 16 + lr) * 64 + lg * 8;
    short8 c0 = *(const short8*)(khi + ka0);
    short8 c1 = *(const short8*)(khi + ka0 + 32);
#pragma unroll
    for (int i = 0; i < 16; ++i) {
      short8 n0, n1;
      if (i < 15) {
        int ka = bhbase + ((jt0 + i + 1) * 16 + lr) * 64 + lg * 8;
        n0 = *(const short8*)(khi + ka);
        n1 = *(const short8*)(khi + ka + 32);
      }
      const uint_t jbase = (uint_t)((jt0 + i) * 16) + jlane;
#pragma unroll
      for (int rs = 0; rs < 2; ++rs) {
        f32x4 aA = {0.f, 0.f, 0.f, 0.f};
        aA = __builtin_amdgcn_mfma_f32_16x16x32_bf16(c0, qh[rs][0], aA, 0, 0, 0);
        aA = __builtin_amdgcn_mfma_f32_16x16x32_bf16(c1, qh[rs][1], aA, 0, 0, 0);
#pragma unroll
        for (int t = 0; t < 4; ++t) {
          uint_t key = (mono_f32(aA[t]) & 0xFFFFFC00u) | (jbase + t);
          insk(key, K[rs][0], K[rs][1], K[rs][2], K[rs][3]);
        }
      }
      if (i < 15) { c0 = n0; c1 = n1; }
    }
  }

  // intra-wave merge of the 4 lane-groups (disjoint j subsets) per q-row
#pragma unroll
  for (int rs = 0; rs < 2; ++rs) {
#pragma unroll
    for (int mask = 16; mask <= 32; mask <<= 1) {
      uint_t o0 = __shfl_xor(K[rs][0], mask), o1 = __shfl_xor(K[rs][1], mask);
      uint_t o2 = __shfl_xor(K[rs][2], mask), o3 = __shfl_xor(K[rs][3], mask);
      insk(o0, K[rs][0], K[rs][1], K[rs][2], K[rs][3]);
      insk(o1, K[rs][0], K[rs][1], K[rs][2], K[rs][3]);
      insk(o2, K[rs][0], K[rs][1], K[rs][2], K[rs][3]);
      insk(o3, K[rs][0], K[rs][1], K[rs][2], K[rs][3]);
    }
    if (l < 16) {
      int r = rowhalf * 32 + rs * 16 + l;
      kL[jq][r][0] = K[rs][0]; kL[jq][r][1] = K[rs][1];
      kL[jq][r][2] = K[rs][2]; kL[jq][r][3] = K[rs][3];
    }
  }
  __syncthreads();

  // ---- Stage B: exact rescore of 16 finalists per row
  // wave w owns rows w*8 .. w*8+7; lane = cand(0..15)*4 + dgroup(0..3)
  {
    const int c16 = l >> 2;
    const int dg = l & 3;
#pragma unroll
    for (int rr = 0; rr < 8; ++rr) {
      int r = w * 8 + rr;
      int j = (int)(kL[c16 >> 2][r][c16 & 3] & 1023u);
      int qa = bhbase + (rg * 64 + r) * 64 + dg * 16;
      int ka = bhbase + j * 64 + dg * 16;
      short8 qh0 = *(const short8*)(qhi + qa);
      short8 qh1 = *(const short8*)(qhi + qa + 8);
      short8 ql0 = *(const short8*)(qlo + qa);
      short8 ql1 = *(const short8*)(qlo + qa + 8);
      short8 kh0 = *(const short8*)(khi + ka);
      short8 kh1 = *(const short8*)(khi + ka + 8);
      short8 kl0 = *(const short8*)(klo + ka);
      short8 kl1 = *(const short8*)(klo + ka + 8);
      float s = 0.f;
#pragma unroll
      for (int e = 0; e < 8; ++e) {
        float qv = bf2f((ushort_t)qh0[e]) + bf2f((ushort_t)ql0[e]);
        float kv = bf2f((ushort_t)kh0[e]) + bf2f((ushort_t)kl0[e]);
        s = fmaf(qv, kv, s);
      }
#pragma unroll
      for (int e = 0; e < 8; ++e) {
        float qv = bf2f((ushort_t)qh1[e]) + bf2f((ushort_t)ql1[e]);
        float kv = bf2f((ushort_t)kh1[e]) + bf2f((ushort_t)kl1[e]);
        s = fmaf(qv, kv, s);
      }
      s += __shfl_xor(s, 1);
      s += __shfl_xor(s, 2);
      if (dg == 0) scL[r][c16] = s;
    }
  }
  __syncthreads();

  // final top-4 over 16 exact scores + softmax (one thread per row)
  if (tid < 64) {
    float s0 = NEG_INF, s1 = NEG_INF, s2 = NEG_INF, s3 = NEG_INF;
    int i0 = 0, i1 = 0, i2 = 0, i3 = 0;
#pragma unroll
    for (int c = 0; c < 16; ++c) {
      float sc = scL[tid][c];
      int jv = (int)(kL[c >> 2][tid][c & 3] & 1023u);
      insert4(sc, jv, s0, s1, s2, s3, i0, i1, i2, i3);
    }
    float m = s0;
    float e0 = expf(s0 - m), e1 = expf(s1 - m);
    float e2 = expf(s2 - m), e3 = expf(s3 - m);
    float inv = 1.f / (e0 + e1 + e2 + e3);
    wgt[tid][0] = e0 * inv; wgt[tid][1] = e1 * inv;
    wgt[tid][2] = e2 * inv; wgt[tid][3] = e3 * inv;
    widx[tid][0] = i0; widx[tid][1] = i1; widx[tid][2] = i2; widx[tid][3] = i3;
  }
  __syncthreads();

  // ---- Stage C: lane = d; gather V, weight, multiply q, accumulate
  const float* vbh = vg + (size_t)bhbase;
  float acc = 0.f;
#pragma unroll
  for (int rr = 0; rr < 8; ++rr) {
    int r = w * 8 + rr;
    float w0 = wgt[r][0], w1 = wgt[r][1], w2 = wgt[r][2], w3 = wgt[r][3];
    int x0 = widx[r][0], x1 = widx[r][1], x2 = widx[r][2], x3 = widx[r][3];
    float wv = w0 * vbh[(size_t)x0 * 64 + l];
    wv = fmaf(w1, vbh[(size_t)x1 * 64 + l], wv);
    wv = fmaf(w2, vbh[(size_t)x2 * 64 + l], wv);
    wv = fmaf(w3, vbh[(size_t)x3 * 64 + l], wv);
    int qa = bhbase + (rg * 64 + r) * 64 + l;
    float qv = bf2f(qhi[qa]) + bf2f(qlo[qa]);
    acc = fmaf(wv, qv, acc);
  }
  accb[w][l] = acc;
  __syncthreads();
  if (w == 0) {
    float tot = accb[0][l] + accb[1][l] + accb[2][l] + accb[3][l] +
                accb[4][l] + accb[5][l] + accb[6][l] + accb[7][l];
    int b = bh >> 3, hh = bh & 7;
    atomicAdd(&out[(size_t)b * Cc + l * Hc + hh], tot);
  }
}

// ---------------------------------------------------------------- launch
extern "C" void kernel_launch(void* const* d_in, const int* in_sizes, int n_in,
                              void* d_out, int out_size, void* d_ws,
                              size_t ws_size, hipStream_t stream) {
  (void)in_sizes; (void)n_in; (void)out_size; (void)ws_size;
  const float* x = (const float*)d_in[0];
  const float* wq = (const float*)d_in[1];
  const float* bias = (const float*)d_in[2];
  float* out = (float*)d_out;

  float* vbuf = (float*)d_ws;               // QSZ f32        (16.8 MB)
  ushort_t* khi = (ushort_t*)(vbuf + QSZ);  // QSZ bf16 each  (8.4 MB x4)
  ushort_t* klo = khi + QSZ;
  ushort_t* qhi = klo + QSZ;
  ushort_t* qlo = qhi + QSZ;
  ushort_t* xth = qlo + QSZ;                // XTSZ bf16 each (8.4 MB x2)
  ushort_t* xtl = xth + XTSZ;
  ushort_t* wth = xtl + XTSZ;               // WTSZ bf16 each (1.6 MB x2)
  ushort_t* wtl = wth + WTSZ;

  zero_out_k<<<dim3((Bc * Cc + 255) / 256), 256, 0, stream>>>(out);
  conv_x<<<dim3(16, 8, 8), 256, 0, stream>>>(x, xth, xtl);
  conv_w<<<dim3(24, 8), 256, 0, stream>>>(wq, wth, wtl);
  qkv_gemm_mfma<<<dim3(64, 12), 256, 0, stream>>>(
      xth, xtl, wth, wtl, bias, vbuf, khi, klo, qhi, qlo);
  attn_topk_mfma<<<dim3(1024), 512, 0, stream>>>(khi, klo, qhi, qlo, vbuf,
                                                 out);
}

// Round 8
// 136.082 us; speedup vs baseline: 1.0727x; 1.0727x over previous
//
#include <hip/hip_runtime.h>

#define NEG_INF (-3.402823466e+38f)

constexpr int Bc = 8, Cc = 512, Hc = 8, Dc = 64, Nc = 1024;
constexpr size_t QSZ = (size_t)Bc * Hc * Nc * Dc;  // 4,194,304 elements
constexpr size_t XTSZ = (size_t)8192 * 512;        // = QSZ
constexpr size_t WTSZ = (size_t)1536 * 512;

typedef __attribute__((ext_vector_type(8))) short short8;
typedef __attribute__((ext_vector_type(4))) float f32x4;
typedef unsigned short ushort_t;
typedef unsigned int uint_t;

// ------------------------------------------------------------ bf16 helpers
__device__ __forceinline__ ushort_t f2bf(float x) {
  uint_t u = __float_as_uint(x);
  u += 0x7FFFu + ((u >> 16) & 1u);  // round-to-nearest-even
  return (ushort_t)(u >> 16);
}
__device__ __forceinline__ float bf2f(ushort_t h) {
  return __uint_as_float(((uint_t)h) << 16);
}

// ---------------------------------------------------------------- zero output
__global__ void zero_out_k(float* __restrict__ o) {
  int i = blockIdx.x * 256 + threadIdx.x;
  if (i < Bc * Cc) o[i] = 0.f;
}

// ------------------------------------------------- transpose+split x -> xt
__global__ __launch_bounds__(256) void conv_x(const float* __restrict__ x,
                                              ushort_t* __restrict__ xh,
                                              ushort_t* __restrict__ xl) {
  __shared__ float t[64][65];
  const int b = blockIdx.z, c0 = blockIdx.y * 64, n0 = blockIdx.x * 64;
  const int tid = threadIdx.x;
  const int lc = tid & 63, lr = tid >> 6;
#pragma unroll
  for (int i = 0; i < 16; ++i) {
    int cc = lr + i * 4;
    t[cc][lc] = x[((size_t)(b * 512 + c0 + cc)) * 1024 + n0 + lc];
  }
  __syncthreads();
#pragma unroll
  for (int i = 0; i < 16; ++i) {
    int nn = lr + i * 4;
    float v = t[lc][nn];  // = x[b][c0+lc][n0+nn]
    ushort_t h = f2bf(v);
    ushort_t lo = f2bf(v - bf2f(h));
    size_t o = ((size_t)(b * 1024 + n0 + nn)) * 512 + c0 + lc;
    xh[o] = h;
    xl[o] = lo;
  }
}

// ------------------------------------------------- transpose+split W -> wt
__global__ __launch_bounds__(256) void conv_w(const float* __restrict__ wq,
                                              ushort_t* __restrict__ wh,
                                              ushort_t* __restrict__ wl) {
  __shared__ float t[64][65];
  const int c0 = blockIdx.y * 64, j0 = blockIdx.x * 64;
  const int tid = threadIdx.x;
  const int lj = tid & 63, lr = tid >> 6;
#pragma unroll
  for (int i = 0; i < 16; ++i) {
    int cc = lr + i * 4;
    t[cc][lj] = wq[(size_t)(c0 + cc) * 1536 + j0 + lj];
  }
  __syncthreads();
#pragma unroll
  for (int i = 0; i < 16; ++i) {
    int jj = lr + i * 4;
    float v = t[lj][jj];  // = W[c0+lj][j0+jj]
    ushort_t h = f2bf(v);
    ushort_t lo = f2bf(v - bf2f(h));
    size_t o = (size_t)(j0 + jj) * 512 + c0 + lj;
    wh[o] = h;
    wl[o] = lo;
  }
}

// ------------------------------------------------------ async stage helper
__device__ __forceinline__ void stage_tile(ushort_t* lds, const ushort_t* g,
                                           int tid) {
  typedef const __attribute__((address_space(1))) unsigned int GU;
  typedef __attribute__((address_space(3))) unsigned int LU;
  {
    int l = tid, r = l >> 2, c = (l & 3) * 8;
    __builtin_amdgcn_global_load_lds((GU*)(g + (size_t)r * 512 + c),
                                     (LU*)(lds + (size_t)l * 8), 16, 0, 0);
  }
  {
    int l = tid + 256, r = l >> 2, c = (l & 3) * 8;
    __builtin_amdgcn_global_load_lds((GU*)(g + (size_t)r * 512 + c),
                                     (LU*)(lds + (size_t)l * 8), 16, 0, 0);
  }
}

// ---------------------------------------------------------------- QKV GEMM
__global__ __launch_bounds__(256) void qkv_gemm_mfma(
    const ushort_t* __restrict__ xth, const ushort_t* __restrict__ xtl,
    const ushort_t* __restrict__ wth, const ushort_t* __restrict__ wtl,
    const float* __restrict__ bias, float* __restrict__ vbuf,
    ushort_t* __restrict__ khi, ushort_t* __restrict__ klo,
    ushort_t* __restrict__ qhi, ushort_t* __restrict__ qlo) {
  __shared__ __align__(16) ushort_t Ah[128 * 32];
  __shared__ __align__(16) ushort_t Al[128 * 32];
  __shared__ __align__(16) ushort_t Bh[128 * 32];
  __shared__ __align__(16) ushort_t Bl[128 * 32];

  const int m0 = blockIdx.x * 128, j0 = blockIdx.y * 128;
  const int tid = threadIdx.x;
  const int w = tid >> 6, l = tid & 63;
  const int lr = l & 15, lg = l >> 4;
  const int wr = w >> 1, wc = w & 1;

  f32x4 acc[4][4];
#pragma unroll
  for (int i = 0; i < 4; ++i)
#pragma unroll
    for (int j = 0; j < 4; ++j) acc[i][j] = (f32x4){0.f, 0.f, 0.f, 0.f};

  const ushort_t* xa = xth + (size_t)m0 * 512;
  const ushort_t* xb = xtl + (size_t)m0 * 512;
  const ushort_t* wa = wth + (size_t)j0 * 512;
  const ushort_t* wb = wtl + (size_t)j0 * 512;

  for (int s = 0; s < 16; ++s) {
    const int k0 = s * 32;
    stage_tile(Ah, xa + k0, tid);
    stage_tile(Al, xb + k0, tid);
    stage_tile(Bh, wa + k0, tid);
    stage_tile(Bl, wb + k0, tid);
    __syncthreads();  // drains vmcnt -> tiles resident

    short8 ah[4], al[4], bh[4], bl[4];
#pragma unroll
    for (int mi = 0; mi < 4; ++mi) {
      int ro = (wr * 64 + mi * 16 + lr) * 32 + lg * 8;
      ah[mi] = *(const short8*)&Ah[ro];
      al[mi] = *(const short8*)&Al[ro];
    }
#pragma unroll
    for (int ji = 0; ji < 4; ++ji) {
      int ro = (wc * 64 + ji * 16 + lr) * 32 + lg * 8;
      bh[ji] = *(const short8*)&Bh[ro];
      bl[ji] = *(const short8*)&Bl[ro];
    }
#pragma unroll
    for (int mi = 0; mi < 4; ++mi)
#pragma unroll
      for (int ji = 0; ji < 4; ++ji) {
        acc[mi][ji] = __builtin_amdgcn_mfma_f32_16x16x32_bf16(
            ah[mi], bh[ji], acc[mi][ji], 0, 0, 0);
        acc[mi][ji] = __builtin_amdgcn_mfma_f32_16x16x32_bf16(
            ah[mi], bl[ji], acc[mi][ji], 0, 0, 0);
        acc[mi][ji] = __builtin_amdgcn_mfma_f32_16x16x32_bf16(
            al[mi], bh[ji], acc[mi][ji], 0, 0, 0);
      }
    __syncthreads();
  }

  const int which = j0 >> 9;
  const int hh = ((j0 >> 6) + wc) & 7;
  float bias_r[4];
#pragma unroll
  for (int ji = 0; ji < 4; ++ji) bias_r[ji] = bias[j0 + wc * 64 + ji * 16 + lr];

#pragma unroll
  for (int mi = 0; mi < 4; ++mi)
#pragma unroll
    for (int t = 0; t < 4; ++t) {
      int m = m0 + wr * 64 + mi * 16 + lg * 4 + t;
      int b = m >> 10, n = m & 1023;
      size_t rb = ((size_t)(b * 8 + hh) << 16) + (size_t)n * 64;
#pragma unroll
      for (int ji = 0; ji < 4; ++ji) {
        float val = acc[mi][ji][t] + bias_r[ji];
        int dd = ji * 16 + lr;
        if (which == 2) {
          vbuf[rb + dd] = val;
        } else {
          ushort_t h = f2bf(val);
          ushort_t lo = f2bf(val - bf2f(h));
          if (which == 0) {
            qhi[rb + dd] = h;
            qlo[rb + dd] = lo;
          } else {
            khi[rb + dd] = h;
            klo[rb + dd] = lo;
          }
        }
      }
    }
}

// ------------------------------------------------------- packed-key top-4
__device__ __forceinline__ uint_t mono_f32(float x) {
  uint_t u = __float_as_uint(x);
  return u ^ (((uint_t)((int)u >> 31)) | 0x80000000u);
}
__device__ __forceinline__ void insk(uint_t k, uint_t& s0, uint_t& s1,
                                     uint_t& s2, uint_t& s3) {
  s3 = max(s3, k);
  uint_t t;
  t = max(s2, s3); s3 = min(s2, s3); s2 = t;
  t = max(s1, s2); s2 = min(s1, s2); s1 = t;
  t = max(s0, s1); s1 = min(s0, s1); s0 = t;
}

// -------------------------------------------------------- float insert4
__device__ __forceinline__ void insert4(float sc, int jv, float& s0, float& s1,
                                        float& s2, float& s3, int& i0, int& i1,
                                        int& i2, int& i3) {
  bool c = sc > s3;
  s3 = c ? sc : s3; i3 = c ? jv : i3;
  c = s3 > s2;
  { float t = c ? s2 : s3; s2 = c ? s3 : s2; s3 = t;
    int q = c ? i2 : i3; i2 = c ? i3 : i2; i3 = q; }
  c = s2 > s1;
  { float t = c ? s1 : s2; s1 = c ? s2 : s1; s2 = t;
    int q = c ? i1 : i2; i1 = c ? i2 : i1; i2 = q; }
  c = s1 > s0;
  { float t = c ? s0 : s1; s0 = c ? s1 : s0; s1 = t;
    int q = c ? i0 : i1; i0 = c ? i1 : i0; i1 = q; }
}

// ---------------------------------------------------------------- fused attn
// grid = 1024 (bh = bid&63 -> same-bh blocks share an XCD; rg = bid>>6).
// 512 thr = 8 waves: (w>>2) = 32-row half, (w&3) = 256-wide j-quarter.
// Stage A (prefilter): 1-pass bf16 scores, K double-buffered in regs,
//   packed-key lane-local top-4, shfl merge -> per-quarter top-4 in LDS.
// Stage B (rescore): 16 finalists/row rescored EXACTLY (hi+lo fp32 dots).
// Stage C: V-gather weighted sum, atomicAdd.
// launch_bounds (512,4): VGPR budget 128 -- (512,6) spilled Stage B to
// scratch (R7: 94MB WRITE_SIZE of spill traffic).
__global__ __launch_bounds__(512, 4) void attn_topk_mfma(
    const ushort_t* __restrict__ khi, const ushort_t* __restrict__ klo,
    const ushort_t* __restrict__ qhi, const ushort_t* __restrict__ qlo,
    const float* __restrict__ vg, float* __restrict__ out) {
  __shared__ uint_t kL[4][64][4];
  __shared__ float scL[64][16];
  __shared__ float wgt[64][4];
  __shared__ int widx[64][4];
  __shared__ float accb[8][64];

  const int bid = blockIdx.x;
  const int bh = bid & 63;
  const int rg = bid >> 6;
  const int tid = threadIdx.x;
  const int w = tid >> 6, l = tid & 63;
  const int lg = l >> 4, lr = l & 15;
  const int jq = w & 3, rowhalf = w >> 2;

  const int bhbase = bh << 16;  // bh * 1024 * 64 (fits int)
  const int rowbase = rg * 64 + rowhalf * 32;

  // Q hi fragments: 2 rowsets x 2 d-chunks (scan uses hi only)
  short8 qh[2][2];
#pragma unroll
  for (int rs = 0; rs < 2; ++rs)
#pragma unroll
    for (int c = 0; c < 2; ++c) {
      int a = bhbase + (rowbase + rs * 16 + lr) * 64 + c * 32 + lg * 8;
      qh[rs][c] = *(const short8*)(qhi + a);
    }

  uint_t K[2][4];
#pragma unroll
  for (int rs = 0; rs < 2; ++rs)
#pragma unroll
    for (int t = 0; t < 4; ++t) K[rs][t] = 0u;

  const uint_t jlane = (uint_t)(lg * 4);
  const int jt0 = jq * 16;

  // ---- Stage A: prefilter scan with register double-buffer of K
  {
    int ka0 = bhbase + (jt0 * 16 + lr) * 64 + lg * 8;
    short8 c0 = *(const short8*)(khi + ka0);
    short8 c1 = *(const short8*)(khi + ka0 + 32);
#pragma unroll
    for (int i = 0; i < 16; ++i) {
      short8 n0, n1;
      if (i < 15) {
        int ka = bhbase + ((jt0 + i + 1) * 16 + lr) * 64 + lg * 8;
        n0 = *(const short8*)(khi + ka);
        n1 = *(const short8*)(khi + ka + 32);
      }
      const uint_t jbase = (uint_t)((jt0 + i) * 16) + jlane;
#pragma unroll
      for (int rs = 0; rs < 2; ++rs) {
        f32x4 aA = {0.f, 0.f, 0.f, 0.f};
        aA = __builtin_amdgcn_mfma_f32_16x16x32_bf16(c0, qh[rs][0], aA, 0, 0, 0);
        aA = __builtin_amdgcn_mfma_f32_16x16x32_bf16(c1, qh[rs][1], aA, 0, 0, 0);
#pragma unroll
        for (int t = 0; t < 4; ++t) {
          uint_t key = (mono_f32(aA[t]) & 0xFFFFFC00u) | (jbase + t);
          insk(key, K[rs][0], K[rs][1], K[rs][2], K[rs][3]);
        }
      }
      if (i < 15) { c0 = n0; c1 = n1; }
    }
  }

  // intra-wave merge of the 4 lane-groups (disjoint j subsets) per q-row
#pragma unroll
  for (int rs = 0; rs < 2; ++rs) {
#pragma unroll
    for (int mask = 16; mask <= 32; mask <<= 1) {
      uint_t o0 = __shfl_xor(K[rs][0], mask), o1 = __shfl_xor(K[rs][1], mask);
      uint_t o2 = __shfl_xor(K[rs][2], mask), o3 = __shfl_xor(K[rs][3], mask);
      insk(o0, K[rs][0], K[rs][1], K[rs][2], K[rs][3]);
      insk(o1, K[rs][0], K[rs][1], K[rs][2], K[rs][3]);
      insk(o2, K[rs][0], K[rs][1], K[rs][2], K[rs][3]);
      insk(o3, K[rs][0], K[rs][1], K[rs][2], K[rs][3]);
    }
    if (l < 16) {
      int r = rowhalf * 32 + rs * 16 + l;
      kL[jq][r][0] = K[rs][0]; kL[jq][r][1] = K[rs][1];
      kL[jq][r][2] = K[rs][2]; kL[jq][r][3] = K[rs][3];
    }
  }
  __syncthreads();

  // ---- Stage B: exact rescore of 16 finalists per row
  // wave w owns rows w*8 .. w*8+7; lane = cand(0..15)*4 + dgroup(0..3)
  {
    const int c16 = l >> 2;
    const int dg = l & 3;
#pragma unroll
    for (int rr = 0; rr < 8; ++rr) {
      int r = w * 8 + rr;
      int j = (int)(kL[c16 >> 2][r][c16 & 3] & 1023u);
      int qa = bhbase + (rg * 64 + r) * 64 + dg * 16;
      int ka = bhbase + j * 64 + dg * 16;
      short8 qh0 = *(const short8*)(qhi + qa);
      short8 qh1 = *(const short8*)(qhi + qa + 8);
      short8 ql0 = *(const short8*)(qlo + qa);
      short8 ql1 = *(const short8*)(qlo + qa + 8);
      short8 kh0 = *(const short8*)(khi + ka);
      short8 kh1 = *(const short8*)(khi + ka + 8);
      short8 kl0 = *(const short8*)(klo + ka);
      short8 kl1 = *(const short8*)(klo + ka + 8);
      float s = 0.f;
#pragma unroll
      for (int e = 0; e < 8; ++e) {
        float qv = bf2f((ushort_t)qh0[e]) + bf2f((ushort_t)ql0[e]);
        float kv = bf2f((ushort_t)kh0[e]) + bf2f((ushort_t)kl0[e]);
        s = fmaf(qv, kv, s);
      }
#pragma unroll
      for (int e = 0; e < 8; ++e) {
        float qv = bf2f((ushort_t)qh1[e]) + bf2f((ushort_t)ql1[e]);
        float kv = bf2f((ushort_t)kh1[e]) + bf2f((ushort_t)kl1[e]);
        s = fmaf(qv, kv, s);
      }
      s += __shfl_xor(s, 1);
      s += __shfl_xor(s, 2);
      if (dg == 0) scL[r][c16] = s;
    }
  }
  __syncthreads();

  // final top-4 over 16 exact scores + softmax (one thread per row)
  if (tid < 64) {
    float s0 = NEG_INF, s1 = NEG_INF, s2 = NEG_INF, s3 = NEG_INF;
    int i0 = 0, i1 = 0, i2 = 0, i3 = 0;
#pragma unroll
    for (int c = 0; c < 16; ++c) {
      float sc = scL[tid][c];
      int jv = (int)(kL[c >> 2][tid][c & 3] & 1023u);
      insert4(sc, jv, s0, s1, s2, s3, i0, i1, i2, i3);
    }
    float m = s0;
    float e0 = expf(s0 - m), e1 = expf(s1 - m);
    float e2 = expf(s2 - m), e3 = expf(s3 - m);
    float inv = 1.f / (e0 + e1 + e2 + e3);
    wgt[tid][0] = e0 * inv; wgt[tid][1] = e1 * inv;
    wgt[tid][2] = e2 * inv; wgt[tid][3] = e3 * inv;
    widx[tid][0] = i0; widx[tid][1] = i1; widx[tid][2] = i2; widx[tid][3] = i3;
  }
  __syncthreads();

  // ---- Stage C: lane = d; gather V, weight, multiply q, accumulate
  const float* vbh = vg + (size_t)bhbase;
  float acc = 0.f;
#pragma unroll
  for (int rr = 0; rr < 8; ++rr) {
    int r = w * 8 + rr;
    float w0 = wgt[r][0], w1 = wgt[r][1], w2 = wgt[r][2], w3 = wgt[r][3];
    int x0 = widx[r][0], x1 = widx[r][1], x2 = widx[r][2], x3 = widx[r][3];
    float wv = w0 * vbh[(size_t)x0 * 64 + l];
    wv = fmaf(w1, vbh[(size_t)x1 * 64 + l], wv);
    wv = fmaf(w2, vbh[(size_t)x2 * 64 + l], wv);
    wv = fmaf(w3, vbh[(size_t)x3 * 64 + l], wv);
    int qa = bhbase + (rg * 64 + r) * 64 + l;
    float qv = bf2f(qhi[qa]) + bf2f(qlo[qa]);
    acc = fmaf(wv, qv, acc);
  }
  accb[w][l] = acc;
  __syncthreads();
  if (w == 0) {
    float tot = accb[0][l] + accb[1][l] + accb[2][l] + accb[3][l] +
                accb[4][l] + accb[5][l] + accb[6][l] + accb[7][l];
    int b = bh >> 3, hh = bh & 7;
    atomicAdd(&out[(size_t)b * Cc + l * Hc + hh], tot);
  }
}

// ---------------------------------------------------------------- launch
extern "C" void kernel_launch(void* const* d_in, const int* in_sizes, int n_in,
                              void* d_out, int out_size, void* d_ws,
                              size_t ws_size, hipStream_t stream) {
  (void)in_sizes; (void)n_in; (void)out_size; (void)ws_size;
  const float* x = (const float*)d_in[0];
  const float* wq = (const float*)d_in[1];
  const float* bias = (const float*)d_in[2];
  float* out = (float*)d_out;

  float* vbuf = (float*)d_ws;               // QSZ f32        (16.8 MB)
  ushort_t* khi = (ushort_t*)(vbuf + QSZ);  // QSZ bf16 each  (8.4 MB x4)
  ushort_t* klo = khi + QSZ;
  ushort_t* qhi = klo + QSZ;
  ushort_t* qlo = qhi + QSZ;
  ushort_t* xth = qlo + QSZ;                // XTSZ bf16 each (8.4 MB x2)
  ushort_t* xtl = xth + XTSZ;
  ushort_t* wth = xtl + XTSZ;               // WTSZ bf16 each (1.6 MB x2)
  ushort_t* wtl = wth + WTSZ;

  zero_out_k<<<dim3((Bc * Cc + 255) / 256), 256, 0, stream>>>(out);
  conv_x<<<dim3(16, 8, 8), 256, 0, stream>>>(x, xth, xtl);
  conv_w<<<dim3(24, 8), 256, 0, stream>>>(wq, wth, wtl);
  qkv_gemm_mfma<<<dim3(64, 12), 256, 0, stream>>>(
      xth, xtl, wth, wtl, bias, vbuf, khi, klo, qhi, qlo);
  attn_topk_mfma<<<dim3(1024), 512, 0, stream>>>(khi, klo, qhi, qlo, vbuf,
                                                 out);
}

// Round 9
// 133.122 us; speedup vs baseline: 1.0965x; 1.0222x over previous
//
#include <hip/hip_runtime.h>

#define NEG_INF (-3.402823466e+38f)

constexpr int Bc = 8, Cc = 512, Hc = 8, Dc = 64, Nc = 1024;
constexpr size_t QSZ = (size_t)Bc * Hc * Nc * Dc;  // 4,194,304 elements
constexpr size_t XTSZ = (size_t)8192 * 512;        // = QSZ
constexpr size_t WTSZ = (size_t)1536 * 512;

typedef __attribute__((ext_vector_type(8))) short short8;
typedef __attribute__((ext_vector_type(4))) float f32x4;
typedef unsigned short ushort_t;
typedef unsigned int uint_t;

// ------------------------------------------------------------ bf16 helpers
__device__ __forceinline__ ushort_t f2bf(float x) {
  uint_t u = __float_as_uint(x);
  u += 0x7FFFu + ((u >> 16) & 1u);  // round-to-nearest-even
  return (ushort_t)(u >> 16);
}
__device__ __forceinline__ float bf2f(ushort_t h) {
  return __uint_as_float(((uint_t)h) << 16);
}

// ---------------------------------------------------------------- zero output
__global__ void zero_out_k(float* __restrict__ o) {
  int i = blockIdx.x * 256 + threadIdx.x;
  if (i < Bc * Cc) o[i] = 0.f;
}

// ------------------------------------------------- transpose+split x -> xt
__global__ __launch_bounds__(256) void conv_x(const float* __restrict__ x,
                                              ushort_t* __restrict__ xh,
                                              ushort_t* __restrict__ xl) {
  __shared__ float t[64][65];
  const int b = blockIdx.z, c0 = blockIdx.y * 64, n0 = blockIdx.x * 64;
  const int tid = threadIdx.x;
  const int lc = tid & 63, lr = tid >> 6;
#pragma unroll
  for (int i = 0; i < 16; ++i) {
    int cc = lr + i * 4;
    t[cc][lc] = x[((size_t)(b * 512 + c0 + cc)) * 1024 + n0 + lc];
  }
  __syncthreads();
#pragma unroll
  for (int i = 0; i < 16; ++i) {
    int nn = lr + i * 4;
    float v = t[lc][nn];  // = x[b][c0+lc][n0+nn]
    ushort_t h = f2bf(v);
    ushort_t lo = f2bf(v - bf2f(h));
    size_t o = ((size_t)(b * 1024 + n0 + nn)) * 512 + c0 + lc;
    xh[o] = h;
    xl[o] = lo;
  }
}

// ------------------------------------------------- transpose+split W -> wt
__global__ __launch_bounds__(256) void conv_w(const float* __restrict__ wq,
                                              ushort_t* __restrict__ wh,
                                              ushort_t* __restrict__ wl) {
  __shared__ float t[64][65];
  const int c0 = blockIdx.y * 64, j0 = blockIdx.x * 64;
  const int tid = threadIdx.x;
  const int lj = tid & 63, lr = tid >> 6;
#pragma unroll
  for (int i = 0; i < 16; ++i) {
    int cc = lr + i * 4;
    t[cc][lj] = wq[(size_t)(c0 + cc) * 1536 + j0 + lj];
  }
  __syncthreads();
#pragma unroll
  for (int i = 0; i < 16; ++i) {
    int jj = lr + i * 4;
    float v = t[lj][jj];  // = W[c0+lj][j0+jj]
    ushort_t h = f2bf(v);
    ushort_t lo = f2bf(v - bf2f(h));
    size_t o = (size_t)(j0 + jj) * 512 + c0 + lj;
    wh[o] = h;
    wl[o] = lo;
  }
}

// ------------------------------------------------------ async stage helper
__device__ __forceinline__ void stage_tile(ushort_t* lds, const ushort_t* g,
                                           int tid) {
  typedef const __attribute__((address_space(1))) unsigned int GU;
  typedef __attribute__((address_space(3))) unsigned int LU;
  {
    int l = tid, r = l >> 2, c = (l & 3) * 8;
    __builtin_amdgcn_global_load_lds((GU*)(g + (size_t)r * 512 + c),
                                     (LU*)(lds + (size_t)l * 8), 16, 0, 0);
  }
  {
    int l = tid + 256, r = l >> 2, c = (l & 3) * 8;
    __builtin_amdgcn_global_load_lds((GU*)(g + (size_t)r * 512 + c),
                                     (LU*)(lds + (size_t)l * 8), 16, 0, 0);
  }
}

// ---------------------------------------------------------------- QKV GEMM
__global__ __launch_bounds__(256) void qkv_gemm_mfma(
    const ushort_t* __restrict__ xth, const ushort_t* __restrict__ xtl,
    const ushort_t* __restrict__ wth, const ushort_t* __restrict__ wtl,
    const float* __restrict__ bias, float* __restrict__ vbuf,
    ushort_t* __restrict__ khi, ushort_t* __restrict__ klo,
    ushort_t* __restrict__ qhi, ushort_t* __restrict__ qlo) {
  __shared__ __align__(16) ushort_t Ah[128 * 32];
  __shared__ __align__(16) ushort_t Al[128 * 32];
  __shared__ __align__(16) ushort_t Bh[128 * 32];
  __shared__ __align__(16) ushort_t Bl[128 * 32];

  const int m0 = blockIdx.x * 128, j0 = blockIdx.y * 128;
  const int tid = threadIdx.x;
  const int w = tid >> 6, l = tid & 63;
  const int lr = l & 15, lg = l >> 4;
  const int wr = w >> 1, wc = w & 1;

  f32x4 acc[4][4];
#pragma unroll
  for (int i = 0; i < 4; ++i)
#pragma unroll
    for (int j = 0; j < 4; ++j) acc[i][j] = (f32x4){0.f, 0.f, 0.f, 0.f};

  const ushort_t* xa = xth + (size_t)m0 * 512;
  const ushort_t* xb = xtl + (size_t)m0 * 512;
  const ushort_t* wa = wth + (size_t)j0 * 512;
  const ushort_t* wb = wtl + (size_t)j0 * 512;

  for (int s = 0; s < 16; ++s) {
    const int k0 = s * 32;
    stage_tile(Ah, xa + k0, tid);
    stage_tile(Al, xb + k0, tid);
    stage_tile(Bh, wa + k0, tid);
    stage_tile(Bl, wb + k0, tid);
    __syncthreads();  // drains vmcnt -> tiles resident

    short8 ah[4], al[4], bh[4], bl[4];
#pragma unroll
    for (int mi = 0; mi < 4; ++mi) {
      int ro = (wr * 64 + mi * 16 + lr) * 32 + lg * 8;
      ah[mi] = *(const short8*)&Ah[ro];
      al[mi] = *(const short8*)&Al[ro];
    }
#pragma unroll
    for (int ji = 0; ji < 4; ++ji) {
      int ro = (wc * 64 + ji * 16 + lr) * 32 + lg * 8;
      bh[ji] = *(const short8*)&Bh[ro];
      bl[ji] = *(const short8*)&Bl[ro];
    }
#pragma unroll
    for (int mi = 0; mi < 4; ++mi)
#pragma unroll
      for (int ji = 0; ji < 4; ++ji) {
        acc[mi][ji] = __builtin_amdgcn_mfma_f32_16x16x32_bf16(
            ah[mi], bh[ji], acc[mi][ji], 0, 0, 0);
        acc[mi][ji] = __builtin_amdgcn_mfma_f32_16x16x32_bf16(
            ah[mi], bl[ji], acc[mi][ji], 0, 0, 0);
        acc[mi][ji] = __builtin_amdgcn_mfma_f32_16x16x32_bf16(
            al[mi], bh[ji], acc[mi][ji], 0, 0, 0);
      }
    __syncthreads();
  }

  const int which = j0 >> 9;
  const int hh = ((j0 >> 6) + wc) & 7;
  float bias_r[4];
#pragma unroll
  for (int ji = 0; ji < 4; ++ji) bias_r[ji] = bias[j0 + wc * 64 + ji * 16 + lr];

#pragma unroll
  for (int mi = 0; mi < 4; ++mi)
#pragma unroll
    for (int t = 0; t < 4; ++t) {
      int m = m0 + wr * 64 + mi * 16 + lg * 4 + t;
      int b = m >> 10, n = m & 1023;
      size_t rb = ((size_t)(b * 8 + hh) << 16) + (size_t)n * 64;
#pragma unroll
      for (int ji = 0; ji < 4; ++ji) {
        float val = acc[mi][ji][t] + bias_r[ji];
        int dd = ji * 16 + lr;
        if (which == 2) {
          vbuf[rb + dd] = val;
        } else {
          ushort_t h = f2bf(val);
          ushort_t lo = f2bf(val - bf2f(h));
          if (which == 0) {
            qhi[rb + dd] = h;
            qlo[rb + dd] = lo;
          } else {
            khi[rb + dd] = h;
            klo[rb + dd] = lo;
          }
        }
      }
    }
}

// ------------------------------------------------------- packed-key top-4
__device__ __forceinline__ uint_t mono_f32(float x) {
  uint_t u = __float_as_uint(x);
  return u ^ (((uint_t)((int)u >> 31)) | 0x80000000u);
}

// sort 4 keys descending (5-comparator network, depth 3)
__device__ __forceinline__ void sort4(uint_t& a, uint_t& b, uint_t& c,
                                      uint_t& d) {
  uint_t t;
  t = max(a, b); b = min(a, b); a = t;
  t = max(c, d); d = min(c, d); c = t;
  t = max(a, c); c = min(a, c); a = t;
  t = max(b, d); d = min(b, d); b = t;
  t = max(b, c); c = min(b, c); b = t;
}

// state s0>=s1>=s2>=s3 (sorted desc); cand a>=b>=c>=d (sorted desc).
// Keep top-4 of the 8, re-sorted desc. Bitonic half-cleaner (4 max) +
// 2-stage bitonic sort (8 ops). Depth ~3 -- replaces 4 serial insert4s.
__device__ __forceinline__ void merge44(uint_t& s0, uint_t& s1, uint_t& s2,
                                        uint_t& s3, uint_t a, uint_t b,
                                        uint_t c, uint_t d) {
  s0 = max(s0, d); s1 = max(s1, c); s2 = max(s2, b); s3 = max(s3, a);
  uint_t t;
  t = max(s0, s2); s2 = min(s0, s2); s0 = t;
  t = max(s1, s3); s3 = min(s1, s3); s1 = t;
  t = max(s0, s1); s1 = min(s0, s1); s0 = t;
  t = max(s2, s3); s3 = min(s2, s3); s2 = t;
}

// -------------------------------------------------------- float insert4
__device__ __forceinline__ void insert4(float sc, int jv, float& s0, float& s1,
                                        float& s2, float& s3, int& i0, int& i1,
                                        int& i2, int& i3) {
  bool c = sc > s3;
  s3 = c ? sc : s3; i3 = c ? jv : i3;
  c = s3 > s2;
  { float t = c ? s2 : s3; s2 = c ? s3 : s2; s3 = t;
    int q = c ? i2 : i3; i2 = c ? i3 : i2; i3 = q; }
  c = s2 > s1;
  { float t = c ? s1 : s2; s1 = c ? s2 : s1; s2 = t;
    int q = c ? i1 : i2; i1 = c ? i2 : i1; i2 = q; }
  c = s1 > s0;
  { float t = c ? s0 : s1; s0 = c ? s1 : s0; s1 = t;
    int q = c ? i0 : i1; i0 = c ? i1 : i0; i1 = q; }
}

// ---------------------------------------------------------------- fused attn
// grid = 1024 (bh = bid&63 -> same-bh blocks share an XCD; rg = bid>>6).
// 512 thr = 8 waves: (w>>2) = 32-row half, (w&3) = 256-wide j-quarter.
// Stage A (prefilter): 1-pass bf16 scores, K double-buffered in regs,
//   packed-key top-4 kept SORTED via sort4+merge44 (short dep chains).
// Stage B (rescore): 16 finalists/row rescored EXACTLY (hi+lo fp32 dots).
// Stage C: V-gather weighted sum, atomicAdd.
// kLp[64][17]: odd stride kills the 4/8-way bank conflicts of [4][64][4].
__global__ __launch_bounds__(512, 4) void attn_topk_mfma(
    const ushort_t* __restrict__ khi, const ushort_t* __restrict__ klo,
    const ushort_t* __restrict__ qhi, const ushort_t* __restrict__ qlo,
    const float* __restrict__ vg, float* __restrict__ out) {
  __shared__ uint_t kLp[64][17];  // [row][q*4+slot], pad to 17
  __shared__ float scL[64][16];
  __shared__ float wgt[64][4];
  __shared__ int widx[64][4];
  __shared__ float accb[8][64];

  const int bid = blockIdx.x;
  const int bh = bid & 63;
  const int rg = bid >> 6;
  const int tid = threadIdx.x;
  const int w = tid >> 6, l = tid & 63;
  const int lg = l >> 4, lr = l & 15;
  const int jq = w & 3, rowhalf = w >> 2;

  const int bhbase = bh << 16;  // bh * 1024 * 64 (fits int)
  const int rowbase = rg * 64 + rowhalf * 32;

  // Q hi fragments: 2 rowsets x 2 d-chunks (scan uses hi only)
  short8 qh[2][2];
#pragma unroll
  for (int rs = 0; rs < 2; ++rs)
#pragma unroll
    for (int c = 0; c < 2; ++c) {
      int a = bhbase + (rowbase + rs * 16 + lr) * 64 + c * 32 + lg * 8;
      qh[rs][c] = *(const short8*)(qhi + a);
    }

  uint_t K[2][4];
#pragma unroll
  for (int rs = 0; rs < 2; ++rs)
#pragma unroll
    for (int t = 0; t < 4; ++t) K[rs][t] = 0u;

  const uint_t jlane = (uint_t)(lg * 4);
  const int jt0 = jq * 16;

  // ---- Stage A: prefilter scan with register double-buffer of K
  {
    int ka0 = bhbase + (jt0 * 16 + lr) * 64 + lg * 8;
    short8 c0 = *(const short8*)(khi + ka0);
    short8 c1 = *(const short8*)(khi + ka0 + 32);
#pragma unroll
    for (int i = 0; i < 16; ++i) {
      short8 n0, n1;
      if (i < 15) {
        int ka = bhbase + ((jt0 + i + 1) * 16 + lr) * 64 + lg * 8;
        n0 = *(const short8*)(khi + ka);
        n1 = *(const short8*)(khi + ka + 32);
      }
      const uint_t jbase = (uint_t)((jt0 + i) * 16) + jlane;
#pragma unroll
      for (int rs = 0; rs < 2; ++rs) {
        f32x4 aA = {0.f, 0.f, 0.f, 0.f};
        aA = __builtin_amdgcn_mfma_f32_16x16x32_bf16(c0, qh[rs][0], aA, 0, 0, 0);
        aA = __builtin_amdgcn_mfma_f32_16x16x32_bf16(c1, qh[rs][1], aA, 0, 0, 0);
        uint_t ca = (mono_f32(aA[0]) & 0xFFFFFC00u) | jbase;
        uint_t cb = (mono_f32(aA[1]) & 0xFFFFFC00u) | (jbase + 1);
        uint_t cc = (mono_f32(aA[2]) & 0xFFFFFC00u) | (jbase + 2);
        uint_t cd = (mono_f32(aA[3]) & 0xFFFFFC00u) | (jbase + 3);
        sort4(ca, cb, cc, cd);
        merge44(K[rs][0], K[rs][1], K[rs][2], K[rs][3], ca, cb, cc, cd);
      }
      if (i < 15) { c0 = n0; c1 = n1; }
    }
  }

  // intra-wave merge of the 4 lane-groups (disjoint j subsets) per q-row.
  // State stays sorted desc -> partner's state is already sorted: merge44.
#pragma unroll
  for (int rs = 0; rs < 2; ++rs) {
#pragma unroll
    for (int mask = 16; mask <= 32; mask <<= 1) {
      uint_t o0 = __shfl_xor(K[rs][0], mask), o1 = __shfl_xor(K[rs][1], mask);
      uint_t o2 = __shfl_xor(K[rs][2], mask), o3 = __shfl_xor(K[rs][3], mask);
      merge44(K[rs][0], K[rs][1], K[rs][2], K[rs][3], o0, o1, o2, o3);
    }
    if (l < 16) {
      int r = rowhalf * 32 + rs * 16 + l;
      kLp[r][jq * 4 + 0] = K[rs][0]; kLp[r][jq * 4 + 1] = K[rs][1];
      kLp[r][jq * 4 + 2] = K[rs][2]; kLp[r][jq * 4 + 3] = K[rs][3];
    }
  }
  __syncthreads();

  // ---- Stage B: exact rescore of 16 finalists per row
  // wave w owns rows w*8 .. w*8+7; lane = cand(0..15)*4 + dgroup(0..3)
  {
    const int c16 = l >> 2;
    const int dg = l & 3;
#pragma unroll
    for (int rr = 0; rr < 8; ++rr) {
      int r = w * 8 + rr;
      int j = (int)(kLp[r][c16] & 1023u);
      int qa = bhbase + (rg * 64 + r) * 64 + dg * 16;
      int ka = bhbase + j * 64 + dg * 16;
      short8 qh0 = *(const short8*)(qhi + qa);
      short8 qh1 = *(const short8*)(qhi + qa + 8);
      short8 ql0 = *(const short8*)(qlo + qa);
      short8 ql1 = *(const short8*)(qlo + qa + 8);
      short8 kh0 = *(const short8*)(khi + ka);
      short8 kh1 = *(const short8*)(khi + ka + 8);
      short8 kl0 = *(const short8*)(klo + ka);
      short8 kl1 = *(const short8*)(klo + ka + 8);
      float s = 0.f;
#pragma unroll
      for (int e = 0; e < 8; ++e) {
        float qv = bf2f((ushort_t)qh0[e]) + bf2f((ushort_t)ql0[e]);
        float kv = bf2f((ushort_t)kh0[e]) + bf2f((ushort_t)kl0[e]);
        s = fmaf(qv, kv, s);
      }
#pragma unroll
      for (int e = 0; e < 8; ++e) {
        float qv = bf2f((ushort_t)qh1[e]) + bf2f((ushort_t)ql1[e]);
        float kv = bf2f((ushort_t)kh1[e]) + bf2f((ushort_t)kl1[e]);
        s = fmaf(qv, kv, s);
      }
      s += __shfl_xor(s, 1);
      s += __shfl_xor(s, 2);
      if (dg == 0) scL[r][c16] = s;
    }
  }
  __syncthreads();

  // final top-4 over 16 exact scores + softmax (one thread per row)
  if (tid < 64) {
    float s0 = NEG_INF, s1 = NEG_INF, s2 = NEG_INF, s3 = NEG_INF;
    int i0 = 0, i1 = 0, i2 = 0, i3 = 0;
#pragma unroll
    for (int c = 0; c < 16; ++c) {
      float sc = scL[tid][c];
      int jv = (int)(kLp[tid][c] & 1023u);
      insert4(sc, jv, s0, s1, s2, s3, i0, i1, i2, i3);
    }
    float m = s0;
    float e0 = expf(s0 - m), e1 = expf(s1 - m);
    float e2 = expf(s2 - m), e3 = expf(s3 - m);
    float inv = 1.f / (e0 + e1 + e2 + e3);
    wgt[tid][0] = e0 * inv; wgt[tid][1] = e1 * inv;
    wgt[tid][2] = e2 * inv; wgt[tid][3] = e3 * inv;
    widx[tid][0] = i0; widx[tid][1] = i1; widx[tid][2] = i2; widx[tid][3] = i3;
  }
  __syncthreads();

  // ---- Stage C: lane = d; gather V, weight, multiply q, accumulate
  const float* vbh = vg + (size_t)bhbase;
  float acc = 0.f;
#pragma unroll
  for (int rr = 0; rr < 8; ++rr) {
    int r = w * 8 + rr;
    float w0 = wgt[r][0], w1 = wgt[r][1], w2 = wgt[r][2], w3 = wgt[r][3];
    int x0 = widx[r][0], x1 = widx[r][1], x2 = widx[r][2], x3 = widx[r][3];
    float wv = w0 * vbh[(size_t)x0 * 64 + l];
    wv = fmaf(w1, vbh[(size_t)x1 * 64 + l], wv);
    wv = fmaf(w2, vbh[(size_t)x2 * 64 + l], wv);
    wv = fmaf(w3, vbh[(size_t)x3 * 64 + l], wv);
    int qa = bhbase + (rg * 64 + r) * 64 + l;
    float qv = bf2f(qhi[qa]) + bf2f(qlo[qa]);
    acc = fmaf(wv, qv, acc);
  }
  accb[w][l] = acc;
  __syncthreads();
  if (w == 0) {
    float tot = accb[0][l] + accb[1][l] + accb[2][l] + accb[3][l] +
                accb[4][l] + accb[5][l] + accb[6][l] + accb[7][l];
    int b = bh >> 3, hh = bh & 7;
    atomicAdd(&out[(size_t)b * Cc + l * Hc + hh], tot);
  }
}

// ---------------------------------------------------------------- launch
extern "C" void kernel_launch(void* const* d_in, const int* in_sizes, int n_in,
                              void* d_out, int out_size, void* d_ws,
                              size_t ws_size, hipStream_t stream) {
  (void)in_sizes; (void)n_in; (void)out_size; (void)ws_size;
  const float* x = (const float*)d_in[0];
  const float* wq = (const float*)d_in[1];
  const float* bias = (const float*)d_in[2];
  float* out = (float*)d_out;

  float* vbuf = (float*)d_ws;               // QSZ f32        (16.8 MB)
  ushort_t* khi = (ushort_t*)(vbuf + QSZ);  // QSZ bf16 each  (8.4 MB x4)
  ushort_t* klo = khi + QSZ;
  ushort_t* qhi = klo + QSZ;
  ushort_t* qlo = qhi + QSZ;
  ushort_t* xth = qlo + QSZ;                // XTSZ bf16 each (8.4 MB x2)
  ushort_t* xtl = xth + XTSZ;
  ushort_t* wth = xtl + XTSZ;               // WTSZ bf16 each (1.6 MB x2)
  ushort_t* wtl = wth + WTSZ;

  zero_out_k<<<dim3((Bc * Cc + 255) / 256), 256, 0, stream>>>(out);
  conv_x<<<dim3(16, 8, 8), 256, 0, stream>>>(x, xth, xtl);
  conv_w<<<dim3(24, 8), 256, 0, stream>>>(wq, wth, wtl);
  qkv_gemm_mfma<<<dim3(64, 12), 256, 0, stream>>>(
      xth, xtl, wth, wtl, bias, vbuf, khi, klo, qhi, qlo);
  attn_topk_mfma<<<dim3(1024), 512, 0, stream>>>(khi, klo, qhi, qlo, vbuf,
                                                 out);
}